// Round 7
// baseline (757.259 us; speedup 1.0000x reference)
//
#include <hip/hip_runtime.h>
#include <hip/hip_bf16.h>
#include <stdint.h>

typedef unsigned short u16;
typedef __bf16 bf16x8 __attribute__((ext_vector_type(8)));
typedef float floatx4 __attribute__((ext_vector_type(4)));

__device__ __forceinline__ u16 f2bf(float f) {
  union { float f; unsigned u; } c; c.f = f;
  unsigned r = c.u + 0x7fffu + ((c.u >> 16) & 1u);
  return (u16)(r >> 16);
}

__device__ __forceinline__ void load_lds16(const void* g, void* l) {
  __builtin_amdgcn_global_load_lds(
      (const __attribute__((address_space(1))) void*)g,
      (__attribute__((address_space(3))) void*)l,
      16, 0, 0);
}

__device__ __forceinline__ void memclob() { asm volatile("" ::: "memory"); }
__device__ __forceinline__ void barrier_() {
  memclob();
  __builtin_amdgcn_s_barrier();
  memclob();
}
// barrier + scheduling fence: nothing (incl. register-only MFMA) crosses.
#define SCHB __builtin_amdgcn_sched_barrier(0)
#define BARS do { barrier_(); SCHB; } while (0)

// ---- preamble: cast x -> bf16 | transpose W0 | transpose W1 | zero z ----
__global__ __launch_bounds__(256) void preamble(
    const float* __restrict__ x, const float* __restrict__ W0,
    const float* __restrict__ W1,
    u16* __restrict__ Xb, u16* __restrict__ Wt0, u16* __restrict__ Wt1,
    float* __restrict__ z)
{
  __shared__ float tile[32][33];
  const int bid = blockIdx.x;
  const int t = threadIdx.x;

  if (bid < 32768) {                      // cast x: 32768*1024 floats, float4/thread
    int i = bid * 256 + t;
    float4 f = ((const float4*)x)[i];
    ushort4 u;
    u.x = f2bf(f.x); u.y = f2bf(f.y); u.z = f2bf(f.z); u.w = f2bf(f.w);
    ((ushort4*)Xb)[i] = u;
  } else if (bid < 32768 + 2048) {        // transpose W0 [1024,2048] -> [2048,1024]
    int tb = bid - 32768;
    int bx = (tb & 63) * 32, by = (tb >> 6) * 32;
    int tx = t & 31, ty = t >> 5;
    #pragma unroll
    for (int i = 0; i < 32; i += 8)
      tile[ty + i][tx] = W0[(size_t)(by + ty + i) * 2048 + bx + tx];
    __syncthreads();
    #pragma unroll
    for (int i = 0; i < 32; i += 8)
      Wt0[(size_t)(bx + ty + i) * 1024 + by + tx] = f2bf(tile[tx][ty + i]);
  } else if (bid < 32768 + 2048 + 4096) { // transpose W1 [2048,2048]
    int tb = bid - (32768 + 2048);
    int bx = (tb & 63) * 32, by = (tb >> 6) * 32;
    int tx = t & 31, ty = t >> 5;
    #pragma unroll
    for (int i = 0; i < 32; i += 8)
      tile[ty + i][tx] = W1[(size_t)(by + ty + i) * 2048 + bx + tx];
    __syncthreads();
    #pragma unroll
    for (int i = 0; i < 32; i += 8)
      Wt1[(size_t)(bx + ty + i) * 2048 + by + tx] = f2bf(tile[tx][ty + i]);
  } else {                                // zero z[32768]
    int tb = bid - (32768 + 2048 + 4096);
    ((float4*)z)[tb * 256 + t] = (float4){0.f, 0.f, 0.f, 0.f};
  }
}

// ======== 256x256 GEMM, 4-barrier K-tile, READS PIPELINED ONE PHASE AHEAD ========
// R6 = R5's verified skeleton (quadrant phases P0=a0xbl P1=a0xbh P2=a1xbl
// P3=a1xbh, 4 barriers/tile, same slots/swizzle/stage schedule/vmcnt(6)
// contract, identical per-element accumulation order) with every ds_read block
// issued one region EARLIER so its return rides an MFMA cluster, not just a
// barrier wait.  R5 cycle model (recalibrated: one 16x16x32 MFMA ~4.85 cyc/CU):
// tile = 5060 cyc measured, MFMA floor 2483 (49% = measured 46% MfmaUtil);
// the gap is LDS return + lgkm waits serialized between barrier and MFMA.
// LDS pipe/tile (~192KB/CU ~ 800-1700 cyc) < MFMA pipe (2483) -> fully
// hideable under MFMA if issued a phase ahead.
//
// Region layout per K-tile t (parity P), content between barriers:
//   seam(t-1->t): reads a0,bl(t) | MFMA_P3(t-1) | reads bh(t) | stage A-hi(t+1)
//   [bar0] MFMA_P0 (a0xbl)  | reads a1(t)
//   [bar1] MFMA_P1 (a0xbh)  | stage A-lo(t+2), B-lo(t+2)
//   [bar2] MFMA_P2 (a1xbl)  | stage B-hi(t+2) | vmcnt(6)
//   [bar3] -> seam(t->t+1)
// Hazard audit (all slots parity-correct, same as R5):
//  RAW: every read targets a slot retired by the vmcnt(6) one tile earlier,
//   globally visible at the preceding barrier.  Seam reads a0',bl' come after
//   bar3 which follows vmcnt(6) retiring ALL of tile t+1's 8 loads (FIFO: 6
//   carried + A-hi@seam(2) + A-lo,B-lo@P1(4) + B-hi@P2(2) = 14 -> wait 6
//   retires oldest 8 = tile t+1).  bh(t) read at seam: B-hi(t) landed one
//   tile ago.  a1(t) read at P0-region: A-hi(t) staged at seam(t-2->t-1),
//   retired by vmcnt at tile t-1.
//  WAR (stage vs prior reads of same slot): A-lo/B-lo(t+2) staged post-bar1:
//   a0/bl(t) reads complete before each wave's MFMA_P0 (< bar1) -> global.
//   B-hi(t+2) post-bar2: bh(t) reads complete before MFMA_P1 (< bar2).
//   A-hi(t+2) at seam post-bar3: a1(t) reads complete before MFMA_P2 (< bar3).
//  Registers: peak live frags 96 (a0+bl+bh+a1 at bar1; a1+bh+a0'+bl' at seam)
//   + acc 128 ~= 244 incl. addressing (2 base ptrs).  WRITE_SIZE = spill canary.
// sched_barrier(0) after each s_barrier pins MFMA below the barrier (rule-#18
// hoisting); seam SCHBs pin [reads a0'bl'] before MFMA_P3 and [reads bh'] after.
template<bool FUSE_HEAD, int KK>
__global__ __launch_bounds__(512, 2) void gemm256_pl(
    const u16* __restrict__ A,      // [M, KK] bf16
    const u16* __restrict__ Bt,     // [N, KK] bf16
    const float* __restrict__ bias, // [N]
    u16* __restrict__ C,            // [M, N] bf16 (unused if FUSE_HEAD)
    const float* __restrict__ W2,   // [N] (used if FUSE_HEAD)
    float* __restrict__ z,          // [M] fp32 accum (used if FUSE_HEAD)
    int M, int N)
{
  __shared__ u16 lds[65536];  // 128 KB; 8 slots x 8192 u16

  const int t = threadIdx.x;
  const int l = t & 63;
  const int w = t >> 6;
  const int wm = w >> 2;       // 0..1
  const int wn = w & 3;        // 0..3
  const int lm = l & 15;
  const int q  = l >> 4;       // 0..3

  // XCD-chunked bijective swizzle; grid = (M/256)*(N/256) = 1024, %8 == 0.
  const int nwg = gridDim.x;
  int wg = blockIdx.x;
  wg = (wg & 7) * (nwg >> 3) + (wg >> 3);
  const int nbn = N >> 8;
  const int n0 = (wg % nbn) << 8;
  const int m0 = (wg / nbn) << 8;

  // ---- staging geometry: per half-tile 2 instrs x 512 thr x 16B = 16 KB.
  // instr n, thread t -> slot-row sr = n*64 + (t>>3), stored chunk t&7,
  // logical chunk (t&7)^((t>>3)&7). ----
  const int rowoff = t >> 3;                     // 0..63
  const int lc8 = ((t & 7) ^ (rowoff & 7)) * 8;  // logical chunk, u16 units
  const int bq = rowoff >> 5;
  const int br = rowoff & 31;
  // 2 running base pointers (R5 used 4; -4 VGPR), advanced 128 u16 per pair.
  // second-instr (+128 rows) offsets are compile-time +128*KK.
  const u16* rA = A  + (size_t)(m0 + rowoff) * KK + lc8;
  const u16* rB = Bt + (size_t)(n0 + bq * 64 + br) * KK + lc8;
  const int ldst = t * 8;                        // u16 dest offset; +4096 for n=1

#define SLOT(p, idx) (((p) * 4 + (idx)) * 8192)  // idx: 0=A-lo 1=A-hi 2=B-lo 3=B-hi

#define STG_A(P, S, KOFF) do {                                                 \
    load_lds16(rA + (S) * 64 * KK + (KOFF), &lds[SLOT(P, S) + ldst]);          \
    load_lds16(rA + (S) * 64 * KK + 128 * KK + (KOFF), &lds[SLOT(P, S) + 4096 + ldst]); \
  } while (0)
#define STG_B(P, S, KOFF) do {                                                 \
    load_lds16(rB + (S) * 32 * KK + (KOFF), &lds[SLOT(P, 2 + (S)) + ldst]);    \
    load_lds16(rB + (S) * 32 * KK + 128 * KK + (KOFF), &lds[SLOT(P, 2 + (S)) + 4096 + ldst]); \
  } while (0)

  // ---- read geometry ----
  const int ck0 = ((0 * 4 + q) ^ (lm & 7)) * 8;  // kk=0 swizzled chunk
  const int ck1 = ((1 * 4 + q) ^ (lm & 7)) * 8;  // kk=1
  const int arow = (wm * 64 + lm) * 64;          // + (i&3)*1024
  const int brow = (wn * 32 + lm) * 64;          // + (j&1)*1024
#define RDA(p, i, ck) (*(const bf16x8*)&lds[SLOT(p, (i) >> 2) + arow + ((i) & 3) * 1024 + (ck)])
#define RDB(p, j, ck) (*(const bf16x8*)&lds[SLOT(p, 2 + ((j) >> 1)) + brow + ((j) & 1) * 1024 + (ck)])
#define MFMA(d, x, y) d = __builtin_amdgcn_mfma_f32_16x16x32_bf16(x, y, d, 0, 0, 0)

  floatx4 acc[8][4];
  #pragma unroll
  for (int i = 0; i < 8; ++i)
    #pragma unroll
    for (int j = 0; j < 4; ++j)
      acc[i][j] = (floatx4){0.f, 0.f, 0.f, 0.f};

  bf16x8 a0[4][2];   // a-lo of current tile (read at previous seam)
  bf16x8 a1[4][2];   // a-hi (read during P0's MFMA window)
  bf16x8 bl[2][2];   // b-lo (read at previous seam)
  bf16x8 bh[2][2];   // b-hi (read at previous seam, after MFMA_P3)

  constexpr int NK = KK >> 6;
  static_assert(NK >= 4 && (NK & 1) == 0, "NK must be even, >= 4");

#define VMW6 asm volatile("s_waitcnt vmcnt(6)" ::: "memory")
#define VMW0 asm volatile("s_waitcnt vmcnt(0)" ::: "memory")
#define VMWN do {} while (0)

  // One K-tile, bar0 .. seam-end.  RDNEXT: read next tile's operands at seam.
  // S2: stage tile t+2 {A-lo,B-lo,B-hi,A-hi} at the audited points, KO = k
  // offset of tile t+2 relative to current pointer base.
#define KTILE(P, RDNEXT, S2, KO, VMW)                                          \
  {                                                                            \
    BARS; /* bar0 */                                                           \
    _Pragma("unroll")                                                          \
    for (int i = 0; i < 4; ++i)                                                \
      _Pragma("unroll")                                                        \
      for (int j = 0; j < 2; ++j) {                                            \
        MFMA(acc[i][j], a0[i][0], bl[j][0]);                                   \
        MFMA(acc[i][j], a0[i][1], bl[j][1]);                                   \
      }                                                                        \
    _Pragma("unroll")                                                          \
    for (int i = 0; i < 4; ++i) { a1[i][0] = RDA(P, 4 + i, ck0); a1[i][1] = RDA(P, 4 + i, ck1); } \
    BARS; /* bar1 */                                                           \
    _Pragma("unroll")                                                          \
    for (int i = 0; i < 4; ++i)                                                \
      _Pragma("unroll")                                                        \
      for (int j = 0; j < 2; ++j) {                                            \
        MFMA(acc[i][2 + j], a0[i][0], bh[j][0]);                               \
        MFMA(acc[i][2 + j], a0[i][1], bh[j][1]);                               \
      }                                                                        \
    if (S2) { STG_A(P, 0, KO); STG_B(P, 0, KO); }                              \
    BARS; /* bar2 */                                                           \
    _Pragma("unroll")                                                          \
    for (int i = 0; i < 4; ++i)                                                \
      _Pragma("unroll")                                                        \
      for (int j = 0; j < 2; ++j) {                                            \
        MFMA(acc[4 + i][j], a1[i][0], bl[j][0]);                               \
        MFMA(acc[4 + i][j], a1[i][1], bl[j][1]);                               \
      }                                                                        \
    SCHB; /* pin: MFMA_P2 issued before stage+vmcnt */                         \
    if (S2) { STG_B(P, 1, KO); }                                               \
    VMW;                                                                       \
    BARS; /* bar3 -> seam */                                                   \
    if (RDNEXT) {                                                              \
      _Pragma("unroll")                                                        \
      for (int i = 0; i < 4; ++i) { a0[i][0] = RDA((P) ^ 1, i, ck0); a0[i][1] = RDA((P) ^ 1, i, ck1); } \
      _Pragma("unroll")                                                        \
      for (int j = 0; j < 2; ++j) { bl[j][0] = RDB((P) ^ 1, j, ck0); bl[j][1] = RDB((P) ^ 1, j, ck1); } \
    }                                                                          \
    SCHB; /* pin: a0',bl' issue before MFMA_P3 (their return hides under it) */\
    _Pragma("unroll")                                                          \
    for (int i = 0; i < 4; ++i)                                                \
      _Pragma("unroll")                                                        \
      for (int j = 0; j < 2; ++j) {                                            \
        MFMA(acc[4 + i][2 + j], a1[i][0], bh[j][0]);                           \
        MFMA(acc[4 + i][2 + j], a1[i][1], bh[j][1]);                           \
      }                                                                        \
    SCHB; /* pin: bh' reads after MFMA_P3 (caps live regs at 96) */            \
    if (RDNEXT) {                                                              \
      _Pragma("unroll")                                                        \
      for (int j = 0; j < 2; ++j) { bh[j][0] = RDB((P) ^ 1, 2 + j, ck0); bh[j][1] = RDB((P) ^ 1, 2 + j, ck1); } \
    }                                                                          \
    if (S2) { STG_A(P, 1, KO); } /* A-hi(t+2): post-bar3, a1(t) reads global */\
  }

  // ---- prologue: stage tile0 x4 + tile1 {A-lo,B-lo,B-hi} (14 instrs);
  // vmcnt(6) retires tile0; then the seam into tile 0: read a0,bl,bh(0) and
  // stage A-hi(1) (8 outstanding entering KTILE(0)).
  STG_A(0, 0, 0); memclob(); STG_A(0, 1, 0); memclob();
  STG_B(0, 0, 0); memclob(); STG_B(0, 1, 0); memclob();
  STG_A(1, 0, 64); memclob(); STG_B(1, 0, 64); memclob(); STG_B(1, 1, 64);
  VMW6;
  BARS;
  #pragma unroll
  for (int i = 0; i < 4; ++i) { a0[i][0] = RDA(0, i, ck0); a0[i][1] = RDA(0, i, ck1); }
  #pragma unroll
  for (int j = 0; j < 2; ++j) { bl[j][0] = RDB(0, j, ck0); bl[j][1] = RDB(0, j, ck1); }
  SCHB;
  #pragma unroll
  for (int j = 0; j < 2; ++j) { bh[j][0] = RDB(0, 2 + j, ck0); bh[j][1] = RDB(0, 2 + j, ck1); }
  STG_A(1, 1, 64);

  // ---- steady state: 2 K-tiles per iteration (compile-time parity).
  // KTILE(t) stages tile t+2 at KO (=128 for parity 0, 192 for parity 1) and
  // reads tile t+1's a0/bl/bh at its seam.  Pointers advance 128 u16 per pair.
  #pragma unroll 1
  for (int g = 0; g < NK - 2; g += 2) {
    KTILE(0, true, true, 128, VMW6);
    KTILE(1, true, true, 192, VMW6);
    rA += 128; rB += 128;
  }
  // tail: tile NK-2 has nothing to stage; its vmcnt(0) drains the 8
  // outstanding (= all of tile NK-1, incl. A-hi staged at the prior seam)
  // before the seam reads tile NK-1's operands.  Tile NK-1: pure compute.
  KTILE(0, true, false, 0, VMW0);
  KTILE(1, false, false, 0, VMWN);

  // ---------------------------- epilogue ----------------------------
  float bv[4];
  #pragma unroll
  for (int j = 0; j < 4; ++j) bv[j] = bias[n0 + wn * 64 + j * 16 + lm];

  if (!FUSE_HEAD) {
    #pragma unroll
    for (int i = 0; i < 8; ++i) {
      #pragma unroll
      for (int r = 0; r < 4; ++r) {
        int grow = m0 + wm * 128 + i * 16 + q * 4 + r;
        size_t base = (size_t)grow * N + n0 + wn * 64 + lm;
        #pragma unroll
        for (int j = 0; j < 4; ++j) {
          float v = acc[i][j][r] + bv[j];
          v = v > 0.f ? v : (__expf(v) - 1.f);
          C[base + j * 16] = f2bf(v);
        }
      }
    }
  } else {
    float w2v[4];
    #pragma unroll
    for (int j = 0; j < 4; ++j) w2v[j] = W2[n0 + wn * 64 + j * 16 + lm];
    #pragma unroll
    for (int i = 0; i < 8; ++i) {
      #pragma unroll
      for (int r = 0; r < 4; ++r) {
        float pacc = 0.f;
        #pragma unroll
        for (int j = 0; j < 4; ++j) {
          float v = acc[i][j][r] + bv[j];
          v = v > 0.f ? v : (__expf(v) - 1.f);
          pacc += v * w2v[j];
        }
        pacc += __shfl_xor(pacc, 1);
        pacc += __shfl_xor(pacc, 2);
        pacc += __shfl_xor(pacc, 4);
        pacc += __shfl_xor(pacc, 8);
        if (lm == 0) atomicAdd(&z[m0 + wm * 128 + i * 16 + q * 4 + r], pacc);
      }
    }
  }
#undef SLOT
#undef STG_A
#undef STG_B
#undef RDA
#undef RDB
#undef MFMA
#undef KTILE
#undef VMW6
#undef VMW0
#undef VMWN
}

// ------------- finish: out = sigmoid(z + b2); alpha = acti(out) -------------
__global__ __launch_bounds__(256) void sigmoid_alpha(
    const float* __restrict__ z, const float* __restrict__ b2,
    float* __restrict__ out, int B)
{
  int i = blockIdx.x * blockDim.x + threadIdx.x;
  if (i >= B) return;
  float o = 1.f / (1.f + expf(-(z[i] + b2[0])));
  float alpha;
  if (o <= 0.2f)      alpha = 0.1f - 0.5f * o;
  else if (o >= 0.8f) alpha = 0.5f * o - 0.4f;
  else                alpha = 0.f;
  out[i] = o;
  out[B + i] = alpha;
}

extern "C" void kernel_launch(void* const* d_in, const int* in_sizes, int n_in,
                              void* d_out, int out_size, void* d_ws, size_t ws_size,
                              hipStream_t stream) {
  const int BATCH = 32768, HID = 2048;

  const float* x  = (const float*)d_in[0];
  const float* W0 = (const float*)d_in[1];
  const float* b0 = (const float*)d_in[2];
  const float* W1 = (const float*)d_in[3];
  const float* b1 = (const float*)d_in[4];
  const float* W2 = (const float*)d_in[5];
  const float* b2 = (const float*)d_in[6];
  float* out = (float*)d_out;

  char* ws = (char*)d_ws;
  u16* Xb   = (u16*)(ws);                       // 64 MB [32768,1024]
  u16* Wt0  = (u16*)(ws + (size_t)67108864);    // 4 MB  [2048,1024]
  u16* Wt1  = (u16*)(ws + (size_t)71303168);    // 8 MB  [2048,2048]
  u16* h0   = (u16*)(ws + (size_t)79691776);    // 128 MB [32768,2048]
  float* z  = (float*)(ws + (size_t)213909504); // 128 KB [32768]

  const int grid = (BATCH / 256) * (HID / 256); // 1024, divisible by 8

  // 1) preamble: cast x, transpose W0/W1, zero z
  preamble<<<32768 + 2048 + 4096 + 32, 256, 0, stream>>>(x, W0, W1, Xb, Wt0, Wt1, z);
  // 2) h0 = elu(Xb @ Wt0^T + b0)
  gemm256_pl<false, 1024><<<grid, 512, 0, stream>>>(
      Xb, Wt0, b0, h0, nullptr, nullptr, BATCH, HID);
  // 3) z += rows of elu(h0 @ Wt1^T + b1) dotted with W2 (h1 never stored)
  gemm256_pl<true, 2048><<<grid, 512, 0, stream>>>(
      h0, Wt1, b1, nullptr, W2, z, BATCH, HID);
  // 4) out + alpha
  sigmoid_alpha<<<BATCH / 256, 256, 0, stream>>>(z, b2, out, BATCH);
}

// Round 8
// 588.091 us; speedup vs baseline: 1.2877x; 1.2877x over previous
//
#include <hip/hip_runtime.h>
#include <hip/hip_bf16.h>
#include <stdint.h>

typedef unsigned short u16;
typedef __bf16 bf16x8 __attribute__((ext_vector_type(8)));
typedef float floatx4 __attribute__((ext_vector_type(4)));

__device__ __forceinline__ u16 f2bf(float f) {
  union { float f; unsigned u; } c; c.f = f;
  unsigned r = c.u + 0x7fffu + ((c.u >> 16) & 1u);
  return (u16)(r >> 16);
}

__device__ __forceinline__ void load_lds16(const void* g, void* l) {
  __builtin_amdgcn_global_load_lds(
      (const __attribute__((address_space(1))) void*)g,
      (__attribute__((address_space(3))) void*)l,
      16, 0, 0);
}

__device__ __forceinline__ void memclob() { asm volatile("" ::: "memory"); }
__device__ __forceinline__ void barrier_() {
  memclob();
  __builtin_amdgcn_s_barrier();
  memclob();
}

// ---- preamble: cast x -> bf16 | transpose W0 | transpose W1 | zero z ----
__global__ __launch_bounds__(256) void preamble(
    const float* __restrict__ x, const float* __restrict__ W0,
    const float* __restrict__ W1,
    u16* __restrict__ Xb, u16* __restrict__ Wt0, u16* __restrict__ Wt1,
    float* __restrict__ z)
{
  __shared__ float tile[32][33];
  const int bid = blockIdx.x;
  const int t = threadIdx.x;

  if (bid < 32768) {                      // cast x: 32768*1024 floats, float4/thread
    int i = bid * 256 + t;
    float4 f = ((const float4*)x)[i];
    ushort4 u;
    u.x = f2bf(f.x); u.y = f2bf(f.y); u.z = f2bf(f.z); u.w = f2bf(f.w);
    ((ushort4*)Xb)[i] = u;
  } else if (bid < 32768 + 2048) {        // transpose W0 [1024,2048] -> [2048,1024]
    int tb = bid - 32768;
    int bx = (tb & 63) * 32, by = (tb >> 6) * 32;
    int tx = t & 31, ty = t >> 5;
    #pragma unroll
    for (int i = 0; i < 32; i += 8)
      tile[ty + i][tx] = W0[(size_t)(by + ty + i) * 2048 + bx + tx];
    __syncthreads();
    #pragma unroll
    for (int i = 0; i < 32; i += 8)
      Wt0[(size_t)(bx + ty + i) * 1024 + by + tx] = f2bf(tile[tx][ty + i]);
  } else if (bid < 32768 + 2048 + 4096) { // transpose W1 [2048,2048]
    int tb = bid - (32768 + 2048);
    int bx = (tb & 63) * 32, by = (tb >> 6) * 32;
    int tx = t & 31, ty = t >> 5;
    #pragma unroll
    for (int i = 0; i < 32; i += 8)
      tile[ty + i][tx] = W1[(size_t)(by + ty + i) * 2048 + bx + tx];
    __syncthreads();
    #pragma unroll
    for (int i = 0; i < 32; i += 8)
      Wt1[(size_t)(bx + ty + i) * 2048 + by + tx] = f2bf(tile[tx][ty + i]);
  } else {                                // zero z[32768]
    int tb = bid - (32768 + 2048 + 4096);
    ((float4*)z)[tb * 256 + t] = (float4){0.f, 0.f, 0.f, 0.f};
  }
}

// ======== 256x256 GEMM, TWO regions per K-tile (2 barriers, 32-MFMA clusters) ========
// R8.  R7 lesson (twice measured, R2+R7): >80 live fragment VGPRs spills
// (WRITE_SIZE 73MB, util 32%).  R5 (80 live, 4 barriers/tile) = 46% util.
// This version pairs phases by A-half:
//   region A (bar_A): reads a0,bl,bh(t) | stage A-hi(t+1) | MFMA P0+P1 (32)
//   region B (bar_B): reads a1(t)       | stage A-lo,B-lo,B-hi(t+2) | MFMA
//                     P2+P3 (32) | vmcnt(6)
// Wins vs R5: (1) live fragments 64 (regA a0+bl+bh, regB bl+bh+a1) < 80 ->
// no spill headroom problem; (2) barriers 4->2 per tile (halve skew);
// (3) each region's reads issue ahead of a 32-MFMA cluster -- first MFMA
// needs 2 of 16 returns; compiler-counted lgkmcnt hides the rest under
// ~1030 cyc of MFMA (reads are IR-visible loads, no inline-asm: compiler
// tracks them; no rule-#18 hazard).
//
// Hazard audit (R3's failure mode checked explicitly -- every stage is
// issued after the barrier that globally follows its slot-readers'
// completion; readers complete before their consuming MFMA in the PRIOR
// region, the closing barrier makes that global):
//   A-hi(t+1) @regA(t): readers a1(t-1) complete < bar_A(t).  OK
//   A-lo,B-lo,B-hi(t+2) @regB(t): readers a0,bl,bh(t) complete < bar_B(t). OK
// RAW: regA(t) reads tile t: all 8 of tile t's loads retired by the
// vmcnt(6) at regB(t-1) (FIFO: 6 carried [A-lo,B-lo,B-hi](t)] + A-hi(t)@
// regA(t-1) + [A-lo,B-lo,B-hi](t+1)@regB(t-1) = 14 -> wait 6 retires the
// oldest 8 = tile t), globally visible after bar_A(t).  regB(t) reads
// A-hi(t): same retire set.  6 loads stay in flight across barriers (T4);
// tail (t=NK-2) drains vmcnt(0); t=NK-1 pure compute.  Issue order per tile
// (A-hi first, then the t+2 trio) identical to R5 -> same FIFO contract.
// Per-accumulator MFMA sequence identical to R5 -> bit-identical output.
template<bool FUSE_HEAD, int KK>
__global__ __launch_bounds__(512, 2) void gemm256_r2(
    const u16* __restrict__ A,      // [M, KK] bf16
    const u16* __restrict__ Bt,     // [N, KK] bf16
    const float* __restrict__ bias, // [N]
    u16* __restrict__ C,            // [M, N] bf16 (unused if FUSE_HEAD)
    const float* __restrict__ W2,   // [N] (used if FUSE_HEAD)
    float* __restrict__ z,          // [M] fp32 accum (used if FUSE_HEAD)
    int M, int N)
{
  __shared__ u16 lds[65536];  // 128 KB; 8 slots x 8192 u16

  const int t = threadIdx.x;
  const int l = t & 63;
  const int w = t >> 6;
  const int wm = w >> 2;       // 0..1
  const int wn = w & 3;        // 0..3
  const int lm = l & 15;
  const int q  = l >> 4;       // 0..3

  // XCD-chunked bijective swizzle; grid = (M/256)*(N/256) = 1024, %8 == 0.
  const int nwg = gridDim.x;
  int wg = blockIdx.x;
  wg = (wg & 7) * (nwg >> 3) + (wg >> 3);
  const int nbn = N >> 8;
  const int n0 = (wg % nbn) << 8;
  const int m0 = (wg / nbn) << 8;

  // ---- staging geometry: per half-tile 2 instrs x 512 thr x 16B = 16 KB.
  // instr n, thread t -> slot-row sr = n*64 + (t>>3), stored chunk t&7,
  // logical chunk (t&7)^((t>>3)&7). ----
  const int rowoff = t >> 3;                     // 0..63
  const int lc8 = ((t & 7) ^ (rowoff & 7)) * 8;  // logical chunk, u16 units
  const int bq = rowoff >> 5;
  const int br = rowoff & 31;
  // running pointers, advanced 128 u16 (2 K-tiles) per loop iteration
  const u16* rA0 = A  + (size_t)(m0 + rowoff) * KK + lc8;
  const u16* rA1 = A  + (size_t)(m0 + 128 + rowoff) * KK + lc8;
  const u16* rB0 = Bt + (size_t)(n0 + bq * 64 + br) * KK + lc8;
  const u16* rB1 = Bt + (size_t)(n0 + (2 + bq) * 64 + br) * KK + lc8;
  const int ldst = t * 8;                        // u16 dest offset; +4096 for n=1

#define SLOT(p, idx) (((p) * 4 + (idx)) * 8192)  // idx: 0=A-lo 1=A-hi 2=B-lo 3=B-hi

#define STG_A(P, S, KOFF) do {                                                 \
    load_lds16(rA0 + (S) * 64 * KK + (KOFF), &lds[SLOT(P, S) + ldst]);         \
    load_lds16(rA1 + (S) * 64 * KK + (KOFF), &lds[SLOT(P, S) + 4096 + ldst]);  \
  } while (0)
#define STG_B(P, S, KOFF) do {                                                 \
    load_lds16(rB0 + (S) * 32 * KK + (KOFF), &lds[SLOT(P, 2 + (S)) + ldst]);   \
    load_lds16(rB1 + (S) * 32 * KK + (KOFF), &lds[SLOT(P, 2 + (S)) + 4096 + ldst]); \
  } while (0)

  // ---- read geometry ----
  const int ck0 = ((0 * 4 + q) ^ (lm & 7)) * 8;  // kk=0 swizzled chunk
  const int ck1 = ((1 * 4 + q) ^ (lm & 7)) * 8;  // kk=1
  const int arow = (wm * 64 + lm) * 64;          // + (i&3)*1024
  const int brow = (wn * 32 + lm) * 64;          // + (j&1)*1024
#define RDA(p, i, ck) (*(const bf16x8*)&lds[SLOT(p, (i) >> 2) + arow + ((i) & 3) * 1024 + (ck)])
#define RDB(p, j, ck) (*(const bf16x8*)&lds[SLOT(p, 2 + ((j) >> 1)) + brow + ((j) & 1) * 1024 + (ck)])
#define MFMA(d, x, y) d = __builtin_amdgcn_mfma_f32_16x16x32_bf16(x, y, d, 0, 0, 0)

  floatx4 acc[8][4];
  #pragma unroll
  for (int i = 0; i < 8; ++i)
    #pragma unroll
    for (int j = 0; j < 4; ++j)
      acc[i][j] = (floatx4){0.f, 0.f, 0.f, 0.f};

  bf16x8 a0[4][2];   // a-lo: live region A only
  bf16x8 a1[4][2];   // a-hi: live region B only
  bf16x8 bl[2][2];   // b-lo: live A..B
  bf16x8 bh[2][2];   // b-hi: live A..B

  constexpr int NK = KK >> 6;
  static_assert(NK >= 4 && (NK & 1) == 0, "NK must be even, >= 4");

#define VMW6 asm volatile("s_waitcnt vmcnt(6)" ::: "memory")
#define VMW0 asm volatile("s_waitcnt vmcnt(0)" ::: "memory")
#define VMWN do {} while (0)

  // One K-tile: 2 regions, one barrier each.
  // SAH/KO1: stage A-hi(t+1) in region A.  S2/KO2: stage tile t+2 trio in
  // region B.  VMW: counted vmcnt at region B end (before next bar_A).
#define KTILE2(P, SAH, KO1, S2, KO2, VMW)                                      \
  {                                                                            \
    barrier_(); /* ---------------- bar_A ---------------- */                  \
    _Pragma("unroll")                                                          \
    for (int i = 0; i < 4; ++i) { a0[i][0] = RDA(P, i, ck0); a0[i][1] = RDA(P, i, ck1); } \
    _Pragma("unroll")                                                          \
    for (int j = 0; j < 2; ++j) { bl[j][0] = RDB(P, j, ck0); bl[j][1] = RDB(P, j, ck1); } \
    _Pragma("unroll")                                                          \
    for (int j = 0; j < 2; ++j) { bh[j][0] = RDB(P, 2 + j, ck0); bh[j][1] = RDB(P, 2 + j, ck1); } \
    if (SAH) { STG_A((P) ^ 1, 1, KO1); }                                       \
    __builtin_amdgcn_s_setprio(1);                                             \
    _Pragma("unroll")                                                          \
    for (int i = 0; i < 4; ++i)                                                \
      _Pragma("unroll")                                                        \
      for (int j = 0; j < 2; ++j) {                                            \
        MFMA(acc[i][j], a0[i][0], bl[j][0]);                                   \
        MFMA(acc[i][j], a0[i][1], bl[j][1]);                                   \
      }                                                                        \
    _Pragma("unroll")                                                          \
    for (int i = 0; i < 4; ++i)                                                \
      _Pragma("unroll")                                                        \
      for (int j = 0; j < 2; ++j) {                                            \
        MFMA(acc[i][2 + j], a0[i][0], bh[j][0]);                               \
        MFMA(acc[i][2 + j], a0[i][1], bh[j][1]);                               \
      }                                                                        \
    __builtin_amdgcn_s_setprio(0);                                             \
    barrier_(); /* ---------------- bar_B ---------------- */                  \
    _Pragma("unroll")                                                          \
    for (int i = 0; i < 4; ++i) { a1[i][0] = RDA(P, 4 + i, ck0); a1[i][1] = RDA(P, 4 + i, ck1); } \
    if (S2) { STG_A(P, 0, KO2); STG_B(P, 0, KO2); STG_B(P, 1, KO2); }          \
    __builtin_amdgcn_s_setprio(1);                                             \
    _Pragma("unroll")                                                          \
    for (int i = 0; i < 4; ++i)                                                \
      _Pragma("unroll")                                                        \
      for (int j = 0; j < 2; ++j) {                                            \
        MFMA(acc[4 + i][j], a1[i][0], bl[j][0]);                               \
        MFMA(acc[4 + i][j], a1[i][1], bl[j][1]);                               \
      }                                                                        \
    _Pragma("unroll")                                                          \
    for (int i = 0; i < 4; ++i)                                                \
      _Pragma("unroll")                                                        \
      for (int j = 0; j < 2; ++j) {                                            \
        MFMA(acc[4 + i][2 + j], a1[i][0], bh[j][0]);                           \
        MFMA(acc[4 + i][2 + j], a1[i][1], bh[j][1]);                           \
      }                                                                        \
    __builtin_amdgcn_s_setprio(0);                                             \
    VMW;                                                                       \
  }

  // ---- prologue: tile0 {A-lo,A-hi,B-lo,B-hi} + tile1 {A-lo,B-lo,B-hi}
  // (A-hi(1) is staged in region A of tile 0).  14 instrs; vmcnt(6) retires
  // the oldest 8 = all of tile 0.  6 in flight entering the loop.
  STG_A(0, 0, 0); memclob(); STG_A(0, 1, 0); memclob();
  STG_B(0, 0, 0); memclob(); STG_B(0, 1, 0); memclob();
  STG_A(1, 0, 64); memclob(); STG_B(1, 0, 64); memclob(); STG_B(1, 1, 64);
  VMW6;

  // ---- steady state: 2 K-tiles per iteration (compile-time parity).
  // tile g   (p=0): A-hi(g+1) @+64,  trio(g+2) @+128, vmcnt(6)
  // tile g+1 (p=1): A-hi(g+2) @+128, trio(g+3) @+192, vmcnt(6)
  #pragma unroll 1
  for (int g = 0; g < NK - 2; g += 2) {
    KTILE2(0, true, 64, true, 128, VMW6);
    KTILE2(1, true, 128, true, 192, VMW6);
    rA0 += 128; rA1 += 128; rB0 += 128; rB1 += 128;
  }
  // tail: tile NK-2 stages only A-hi(NK-1); vmcnt(0) drains the 8
  // outstanding (= all of tile NK-1).  Tile NK-1: pure compute.
  KTILE2(0, true, 64, false, 0, VMW0);
  KTILE2(1, false, 0, false, 0, VMWN);

  // ---------------------------- epilogue ----------------------------
  float bv[4];
  #pragma unroll
  for (int j = 0; j < 4; ++j) bv[j] = bias[n0 + wn * 64 + j * 16 + lm];

  if (!FUSE_HEAD) {
    #pragma unroll
    for (int i = 0; i < 8; ++i) {
      #pragma unroll
      for (int r = 0; r < 4; ++r) {
        int grow = m0 + wm * 128 + i * 16 + q * 4 + r;
        size_t base = (size_t)grow * N + n0 + wn * 64 + lm;
        #pragma unroll
        for (int j = 0; j < 4; ++j) {
          float v = acc[i][j][r] + bv[j];
          v = v > 0.f ? v : (__expf(v) - 1.f);
          C[base + j * 16] = f2bf(v);
        }
      }
    }
  } else {
    float w2v[4];
    #pragma unroll
    for (int j = 0; j < 4; ++j) w2v[j] = W2[n0 + wn * 64 + j * 16 + lm];
    #pragma unroll
    for (int i = 0; i < 8; ++i) {
      #pragma unroll
      for (int r = 0; r < 4; ++r) {
        float pacc = 0.f;
        #pragma unroll
        for (int j = 0; j < 4; ++j) {
          float v = acc[i][j][r] + bv[j];
          v = v > 0.f ? v : (__expf(v) - 1.f);
          pacc += v * w2v[j];
        }
        pacc += __shfl_xor(pacc, 1);
        pacc += __shfl_xor(pacc, 2);
        pacc += __shfl_xor(pacc, 4);
        pacc += __shfl_xor(pacc, 8);
        if (lm == 0) atomicAdd(&z[m0 + wm * 128 + i * 16 + q * 4 + r], pacc);
      }
    }
  }
#undef SLOT
#undef STG_A
#undef STG_B
#undef RDA
#undef RDB
#undef MFMA
#undef KTILE2
#undef VMW6
#undef VMW0
#undef VMWN
}

// ------------- finish: out = sigmoid(z + b2); alpha = acti(out) -------------
__global__ __launch_bounds__(256) void sigmoid_alpha(
    const float* __restrict__ z, const float* __restrict__ b2,
    float* __restrict__ out, int B)
{
  int i = blockIdx.x * blockDim.x + threadIdx.x;
  if (i >= B) return;
  float o = 1.f / (1.f + expf(-(z[i] + b2[0])));
  float alpha;
  if (o <= 0.2f)      alpha = 0.1f - 0.5f * o;
  else if (o >= 0.8f) alpha = 0.5f * o - 0.4f;
  else                alpha = 0.f;
  out[i] = o;
  out[B + i] = alpha;
}

extern "C" void kernel_launch(void* const* d_in, const int* in_sizes, int n_in,
                              void* d_out, int out_size, void* d_ws, size_t ws_size,
                              hipStream_t stream) {
  const int BATCH = 32768, HID = 2048;

  const float* x  = (const float*)d_in[0];
  const float* W0 = (const float*)d_in[1];
  const float* b0 = (const float*)d_in[2];
  const float* W1 = (const float*)d_in[3];
  const float* b1 = (const float*)d_in[4];
  const float* W2 = (const float*)d_in[5];
  const float* b2 = (const float*)d_in[6];
  float* out = (float*)d_out;

  char* ws = (char*)d_ws;
  u16* Xb   = (u16*)(ws);                       // 64 MB [32768,1024]
  u16* Wt0  = (u16*)(ws + (size_t)67108864);    // 4 MB  [2048,1024]
  u16* Wt1  = (u16*)(ws + (size_t)71303168);    // 8 MB  [2048,2048]
  u16* h0   = (u16*)(ws + (size_t)79691776);    // 128 MB [32768,2048]
  float* z  = (float*)(ws + (size_t)213909504); // 128 KB [32768]

  const int grid = (BATCH / 256) * (HID / 256); // 1024, divisible by 8

  // 1) preamble: cast x, transpose W0/W1, zero z
  preamble<<<32768 + 2048 + 4096 + 32, 256, 0, stream>>>(x, W0, W1, Xb, Wt0, Wt1, z);
  // 2) h0 = elu(Xb @ Wt0^T + b0)
  gemm256_r2<false, 1024><<<grid, 512, 0, stream>>>(
      Xb, Wt0, b0, h0, nullptr, nullptr, BATCH, HID);
  // 3) z += rows of elu(h0 @ Wt1^T + b1) dotted with W2 (h1 never stored)
  gemm256_r2<true, 2048><<<grid, 512, 0, stream>>>(
      h0, Wt1, b1, nullptr, W2, z, BATCH, HID);
  // 4) out + alpha
  sigmoid_alpha<<<BATCH / 256, 256, 0, stream>>>(z, b2, out, BATCH);
}